// Round 3
// baseline (494.243 us; speedup 1.0000x reference)
//
#include <hip/hip_runtime.h>

#define TPB 256

// ---------------- LDS arena layout (float offsets) ----------------
// hpad_i (zero-padded, s-modulated input of layer i) always at 0:
//   hpad0 [32][6][6]   = 1152
//   hpad1 [16][10][10] = 1600
//   hpad2 [8][18][18]  = 2592
//   hpad3 [4][34][34]  = 4624
// raw conv outputs c_i (disjoint from hpad_i AND hpad_{i+1}):
//   c0 [16][4][4]  @ 1600..1856
//   c1 [8][8][8]   @ 2592..3104
//   c2 [4][16][16] @ 4624..5648
//   c3 [4][32][32] @ 4624..8720
// weight buffers (padded row stride CIN*9+1, loaded one layer ahead):
//   w0 16x289=4624 @ 1856..6480   (loaded in P1)
//   w1  8x145=1160 @ 3104..4264   (loaded during UP0)
//   w2  4x73 = 292 @ 3104..3396   (loaded during UP1)
//   w3  4x37 = 148 @ 8720..8868   (loaded during UP2)
// misc: style[32]@8880, s_all[60]@8912 (s0+0,s1+32,s2+48,s3+56),
//       demod[32]@8972 (d0+0,d1+16,d2+24,d3+28)
constexpr int M_STYLE = 8880;
constexpr int M_S     = 8912;
constexpr int M_D     = 8972;
constexpr int LDSF    = 9008;   // 36 KB -> 4 blocks/CU

template<int CIN, int COUT, int H, int R>
__device__ __forceinline__ void conv3x3(const float* __restrict__ hp,
                                        const float* __restrict__ wb,
                                        float* __restrict__ c, int tid)
{
    constexpr int W = H, HS = H + 2;
    constexpr int LW = (W==4)?2:((W==8)?3:((W==16)?4:5));
    constexpr int LC = (COUT==16)?4:((COUT==8)?3:2);
    constexpr int WS = CIN*9 + 1;            // padded weight row stride
    const int xx = tid & (W-1);
    const int co = (tid >> LW) & (COUT-1);
    const int y0 = (tid >> (LW+LC)) * R;     // row strip start
    float acc[R];
#pragma unroll
    for (int r = 0; r < R; r++) acc[r] = 0.f;
    const float* wco = wb + co*WS;
#pragma unroll
    for (int ci = 0; ci < CIN; ci++) {
        const float* hc = hp + ci*HS*HS + xx;
#pragma unroll
        for (int dx = 0; dx < 3; dx++) {
            float col[R+2];
#pragma unroll
            for (int r = 0; r < R+2; r++) col[r] = hc[(y0+r)*HS + dx];
#pragma unroll
            for (int dy = 0; dy < 3; dy++) {
                const float wv = wco[ci*9 + dy*3 + dx];
#pragma unroll
                for (int r = 0; r < R; r++) acc[r] = fmaf(wv, col[r+dy], acc[r]);
            }
        }
    }
#pragma unroll
    for (int r = 0; r < R; r++) c[co*H*W + (y0+r)*W + xx] = acc[r];
}

// bilinear x2 (half-pixel, edge-clamped == jax renormalized edges), applies demod,
// writes global feat (float2) and, if !LAST, s_next-modulated interior of hpad_{i+1}.
template<int COUT, int H, bool LAST>
__device__ __forceinline__ void upsample(const float* __restrict__ c,
                                         const float* __restrict__ dmv,
                                         const float* __restrict__ snext,
                                         float* __restrict__ hnext,
                                         float* __restrict__ gout, int tid)
{
    constexpr int W = H;
    constexpr int LW = (W==4)?2:((W==8)?3:((W==16)?4:5));
    constexpr int LC = (COUT==16)?4:((COUT==8)?3:2);
    constexpr int STRIPS = 256/(W*COUT);
    constexpr int KQ = H / STRIPS;           // quad-rows per thread
    constexpr int NS = 2*H + 2;              // next hpad row stride
    const int p  = tid & (W-1);              // pair (quad-col) index
    const int co = (tid >> LW) & (COUT-1);
    const int k0 = (tid >> (LW+LC)) * KQ;
    const float dm = dmv[co];
    float sn = 0.f;
    if constexpr (!LAST) sn = snext[co];
    const int xm = (p==0) ? 0 : p-1;
    const int xp = (p==W-1) ? W-1 : p+1;
    const float* cc = c + co*H*W;
#pragma unroll
    for (int k = k0; k < k0+KQ; k++) {
        const int km = (k==0) ? 0 : k-1;
        const int kp = (k==H-1) ? H-1 : k+1;
        const float am = cc[km*W+xm], a0 = cc[km*W+p], ap = cc[km*W+xp];
        const float bm = cc[k *W+xm], b0 = cc[k *W+p], bp = cc[k *W+xp];
        const float em = cc[kp*W+xm], e0 = cc[kp*W+p], ep = cc[kp*W+xp];
        // vertical blends: out row 2k: 0.25*r[k-1]+0.75*r[k]; row 2k+1: 0.75*r[k]+0.25*r[k+1]
        const float tm0 = 0.25f*am + 0.75f*bm, t00 = 0.25f*a0 + 0.75f*b0, tp0 = 0.25f*ap + 0.75f*bp;
        const float tm1 = 0.75f*bm + 0.25f*em, t01 = 0.75f*b0 + 0.25f*e0, tp1 = 0.75f*bp + 0.25f*ep;
        const float o00 = (0.25f*tm0 + 0.75f*t00) * dm;
        const float o01 = (0.75f*t00 + 0.25f*tp0) * dm;
        const float o10 = (0.25f*tm1 + 0.75f*t01) * dm;
        const float o11 = (0.75f*t01 + 0.25f*tp1) * dm;
        float* g = gout + co*(4*H*W) + (2*k)*(2*W) + 2*p;
        *(float2*)g          = make_float2(o00, o01);
        *(float2*)(g + 2*W)  = make_float2(o10, o11);
        if constexpr (!LAST) {
            float* hb = hnext + co*NS*NS + (2*k+1)*NS + (2*p+1);
            hb[0]    = o00*sn;  hb[1]    = o01*sn;
            hb[NS]   = o10*sn;  hb[NS+1] = o11*sn;
        }
    }
}

template<int C, int NS>
__device__ __forceinline__ void zero_halo(float* hn, int tid)
{
    for (int j = tid; j < C*NS*NS; j += TPB) {
        const int r = j % (NS*NS);
        const int y = r / NS, x2 = r % NS;
        if (y == 0 || y == NS-1 || x2 == 0 || x2 == NS-1) hn[j] = 0.f;
    }
}

template<int CIN, int COUT>
__device__ __forceinline__ void load_w(const float* __restrict__ g, float* __restrict__ wb, int tid)
{
    constexpr int N = COUT*CIN*9;
    for (int j = tid; j < N; j += TPB) {
        const int co = j / (CIN*9);
        wb[co*(CIN*9+1) + (j - co*(CIN*9))] = g[j];
    }
}

__global__ void __launch_bounds__(TPB)
decoder_kernel(const float* __restrict__ x,   const float* __restrict__ fc_w,
               const float* __restrict__ fc_b,const float* __restrict__ cst,
               const float* __restrict__ cw0, const float* __restrict__ mw0, const float* __restrict__ mb0,
               const float* __restrict__ cw1, const float* __restrict__ mw1, const float* __restrict__ mb1,
               const float* __restrict__ cw2, const float* __restrict__ mw2, const float* __restrict__ mb2,
               const float* __restrict__ cw3, const float* __restrict__ mw3, const float* __restrict__ mb3,
               float* __restrict__ f0, float* __restrict__ f1,
               float* __restrict__ f2, float* __restrict__ f3)
{
    __shared__ float lds[LDSF];
    const int tid = threadIdx.x;
    const int b   = blockIdx.x;

    // P0: style = x @ fc_w.T + fc_b
    if (tid < 32) {
        const float* xr = x + (size_t)b*32;
        const float* fw = fc_w + tid*32;
        float acc = fc_b[tid];
#pragma unroll
        for (int k = 0; k < 32; k++) acc = fmaf(xr[k], fw[k], acc);
        lds[M_STYLE + tid] = acc;
    }
    __syncthreads();

    // P1: s_all (60 values) + stage w0 into LDS
    if (tid < 60) {
        int ci; const float* mwp; const float* mbp;
        if (tid < 32)      { ci = tid;      mwp = mw0; mbp = mb0; }
        else if (tid < 48) { ci = tid - 32; mwp = mw1; mbp = mb1; }
        else if (tid < 56) { ci = tid - 48; mwp = mw2; mbp = mb2; }
        else               { ci = tid - 56; mwp = mw3; mbp = mb3; }
        mwp += ci*32;
        float acc = mbp[ci];
#pragma unroll
        for (int k = 0; k < 32; k++) acc = fmaf(lds[M_STYLE + k], mwp[k], acc);
        lds[M_S + tid] = acc;
    }
    load_w<32,16>(cw0, &lds[1856], tid);
    __syncthreads();

    // P2: demod (32 outputs, 8 threads each) + hpad0 = s0 * const (zero halo)
    {
        const int g = tid >> 3, l = tid & 7;
        int co, cin; const float* wp; const float* sp;
        if (g < 16)      { co = g;      cin = 32; wp = cw0; sp = &lds[M_S];      }
        else if (g < 24) { co = g - 16; cin = 16; wp = cw1; sp = &lds[M_S + 32]; }
        else if (g < 28) { co = g - 24; cin = 8;  wp = cw2; sp = &lds[M_S + 48]; }
        else             { co = g - 28; cin = 4;  wp = cw3; sp = &lds[M_S + 56]; }
        wp += co*cin*9;
        float acc = 0.f;
        for (int e = l; e < cin*9; e += 8) {
            const int ci = e / 9;
            const float wv = wp[e] * sp[ci];
            acc = fmaf(wv, wv, acc);
        }
        acc += __shfl_xor(acc, 1);
        acc += __shfl_xor(acc, 2);
        acc += __shfl_xor(acc, 4);
        if (l == 0) lds[M_D + g] = rsqrtf(acc + 1e-8f);
    }
    for (int j = tid; j < 1152; j += TPB) {          // hpad0 [32][6][6]
        const int ci = j / 36, r = j - ci*36, y = r / 6, x2 = r - y*6;
        float v = 0.f;
        if (y >= 1 && y <= 4 && x2 >= 1 && x2 <= 4)
            v = lds[M_S + ci] * cst[ci*16 + (y-1)*4 + (x2-1)];
        lds[j] = v;
    }
    __syncthreads();

    // ---- layer 0: [32,4,4] -> conv [16,4,4] -> up [16,8,8] ----
    conv3x3<32,16,4,1>(&lds[0], &lds[1856], &lds[1600], tid);
    __syncthreads();
    upsample<16,4,false>(&lds[1600], &lds[M_D], &lds[M_S + 32], &lds[0],
                         f0 + (size_t)b*1024, tid);
    zero_halo<16,10>(&lds[0], tid);
    load_w<16,8>(cw1, &lds[3104], tid);
    __syncthreads();

    // ---- layer 1: [16,8,8] -> conv [8,8,8] -> up [8,16,16] ----
    conv3x3<16,8,8,2>(&lds[0], &lds[3104], &lds[2592], tid);
    __syncthreads();
    upsample<8,8,false>(&lds[2592], &lds[M_D + 16], &lds[M_S + 48], &lds[0],
                        f1 + (size_t)b*2048, tid);
    zero_halo<8,18>(&lds[0], tid);
    load_w<8,4>(cw2, &lds[3104], tid);
    __syncthreads();

    // ---- layer 2: [8,16,16] -> conv [4,16,16] -> up [4,32,32] ----
    conv3x3<8,4,16,4>(&lds[0], &lds[3104], &lds[4624], tid);
    __syncthreads();
    upsample<4,16,false>(&lds[4624], &lds[M_D + 24], &lds[M_S + 56], &lds[0],
                         f2 + (size_t)b*4096, tid);
    zero_halo<4,34>(&lds[0], tid);
    load_w<4,4>(cw3, &lds[8720], tid);
    __syncthreads();

    // ---- layer 3: [4,32,32] -> conv [4,32,32] -> up [4,64,64] ----
    conv3x3<4,4,32,16>(&lds[0], &lds[8720], &lds[4624], tid);
    __syncthreads();
    upsample<4,32,true>(&lds[4624], &lds[M_D + 28], nullptr, nullptr,
                        f3 + (size_t)b*16384, tid);
}

extern "C" void kernel_launch(void* const* d_in, const int* in_sizes, int n_in,
                              void* d_out, int out_size, void* d_ws, size_t ws_size,
                              hipStream_t stream)
{
    const float* x    = (const float*)d_in[0];
    const float* fc_w = (const float*)d_in[1];
    const float* fc_b = (const float*)d_in[2];
    const float* cst  = (const float*)d_in[3];
    const float* cw0  = (const float*)d_in[4];
    const float* mw0  = (const float*)d_in[5];
    const float* mb0  = (const float*)d_in[6];
    const float* cw1  = (const float*)d_in[7];
    const float* mw1  = (const float*)d_in[8];
    const float* mb1  = (const float*)d_in[9];
    const float* cw2  = (const float*)d_in[10];
    const float* mw2  = (const float*)d_in[11];
    const float* mb2  = (const float*)d_in[12];
    const float* cw3  = (const float*)d_in[13];
    const float* mw3  = (const float*)d_in[14];
    const float* mb3  = (const float*)d_in[15];
    float* out = (float*)d_out;

    const int Bn = in_sizes[0] / 32;                 // 4096
    float* f0 = out;
    float* f1 = f0 + (size_t)Bn*1024;
    float* f2 = f1 + (size_t)Bn*2048;
    float* f3 = f2 + (size_t)Bn*4096;

    decoder_kernel<<<dim3(Bn), dim3(TPB), 0, stream>>>(
        x, fc_w, fc_b, cst,
        cw0, mw0, mb0, cw1, mw1, mb1, cw2, mw2, mb2, cw3, mw3, mb3,
        f0, f1, f2, f3);
}